// Round 5
// baseline (932.113 us; speedup 1.0000x reference)
//
#include <hip/hip_runtime.h>
#include <hip/hip_cooperative_groups.h>
#include <hip/hip_bf16.h>
#include <cstdint>

namespace coop = cooperative_groups;

#define NV 20000
#define NE 40000
#define NODE_IN 74
#define EDGE_IN 12
#define D 64
#define EHID 128
#define NSTEPS 6

typedef __bf16 bf16x8 __attribute__((ext_vector_type(8)));
typedef float f32x4 __attribute__((ext_vector_type(4)));

// ------- fused prep: proj | edge1 | cvt_w2 | b2t | build_b (all independent) -------
__global__ __launch_bounds__(256) void k_prep(
    const float* __restrict__ nf, const float* __restrict__ pjW, const float* __restrict__ pjb,
    float* __restrict__ h, float* __restrict__ neigh,
    const float* __restrict__ ef, const float* __restrict__ W1, const float* __restrict__ b1,
    __hip_bfloat16* __restrict__ t_bf,
    const float* __restrict__ W2, __hip_bfloat16* __restrict__ w2b,
    const float* __restrict__ b2, __hip_bfloat16* __restrict__ b2t,
    const float* __restrict__ Wih, const float* __restrict__ Whh,
    __hip_bfloat16* __restrict__ Bhi, __hip_bfloat16* __restrict__ Blo) {
  __shared__ float smem[4 * NODE_IN];
  int tid = threadIdx.x;
  int bx = blockIdx.x;
  if (bx < 5000) {                    // ---- node projection: 4 nodes/block ----
    int nb = bx * 4;
    for (int idx = tid; idx < 4 * NODE_IN; idx += 256)
      smem[idx] = nf[(size_t)nb * NODE_IN + idx];
    __syncthreads();
    int nl = tid >> 6, o = tid & 63;
    float acc = pjb[o];
#pragma unroll
    for (int i = 0; i < NODE_IN; ++i) acc = fmaf(smem[nl * NODE_IN + i], pjW[o * NODE_IN + i], acc);
    h[(size_t)(nb + nl) * D + o] = fmaxf(acc, 0.f);
    neigh[(size_t)(nb + nl) * D + o] = 0.f;
  } else if (bx < 25000) {            // ---- edge net layer 1: 2 edges/block ----
    int eb = (bx - 5000) * 2;
    if (tid < 2 * EDGE_IN)
      smem[tid] = ef[(size_t)eb * EDGE_IN + tid];
    __syncthreads();
    int el = tid >> 7, k = tid & 127;
    float acc = b1[k];
#pragma unroll
    for (int j = 0; j < EDGE_IN; ++j) acc = fmaf(smem[el * EDGE_IN + j], W1[k * EDGE_IN + j], acc);
    t_bf[(size_t)(eb + el) * EHID + k] = __float2bfloat16(fmaxf(acc, 0.f));
  } else if (bx < 27048) {            // ---- W2 fp32 -> bf16 ----
    int idx = (bx - 25000) * 256 + tid;
    w2b[idx] = __float2bfloat16(W2[idx]);
  } else if (bx < 27064) {            // ---- b2 transpose ----
    int idx = (bx - 27048) * 256 + tid;
    int o = idx >> 6, i = idx & 63;
    b2t[o * 64 + i] = __float2bfloat16(b2[i * 64 + o]);
  } else {                            // ---- GRU B matrix, hi/lo split ----
    int idx = (bx - 27064) * 256 + tid;
    int n = idx >> 7, k = idx & 127;
    int o = n & 63, cls = n >> 6;
    float v;
    if (cls == 0)      v = (k < 64) ? Wih[o * 64 + k]         : Whh[o * 64 + (k - 64)];
    else if (cls == 1) v = (k < 64) ? Wih[(64 + o) * 64 + k]  : Whh[(64 + o) * 64 + (k - 64)];
    else if (cls == 2) v = (k < 64) ? Wih[(128 + o) * 64 + k] : 0.f;
    else               v = (k < 64) ? 0.f                     : Whh[(128 + o) * 64 + (k - 64)];
    __hip_bfloat16 hi = __float2bfloat16(v);
    Bhi[idx] = hi;
    Blo[idx] = __float2bfloat16(v - __bfloat162float(hi));
  }
}

// ======= ONE cooperative kernel: 6 x (msg -> grid.sync -> gru -> grid.sync) + pred =======
// R0-5: the 14-dispatch pipeline had ~125-165us of launch/serialization overhead
// (non-k_msg time 225us vs ~60-100us of real work). Fuse the whole step loop + pred
// into one cooperative kernel: 256 blocks x 512 thr, 144KB LDS -> exactly 1 block/CU
// -> co-residency guaranteed. grid.sync() replaces 11 kernel boundaries.
// msg body = proven R0 shape (512thr, 64e x 32i x 16o tiles, barrier-free rounds,
// bf16 Hs + shift/mask postscale) + setprio + src/dst hoists. GRU overlays its
// A-tiles in W2s[0..16383] (2 groups x 4 waves, 2 reps -> 625 groups); W2s rows
// 0..127 partially reloaded each step (4/16 chunks). All math bit-identical to R4.
__global__ __launch_bounds__(512, 2) void k_steps(
    float* __restrict__ h, const __hip_bfloat16* __restrict__ t_bf,
    const __hip_bfloat16* __restrict__ w2, const __hip_bfloat16* __restrict__ b2t,
    const int* __restrict__ src, const int* __restrict__ dst,
    float* __restrict__ neigh,
    const __hip_bfloat16* __restrict__ Bhi, const __hip_bfloat16* __restrict__ Blo,
    const float* __restrict__ cb, const float* __restrict__ bih, const float* __restrict__ bhh,
    const float* __restrict__ pW, const float* __restrict__ pb, float* __restrict__ out) {
  coop::grid_group grid = coop::this_grid();
  __shared__ __hip_bfloat16 W2s[512 * 128];   // 128 KB; first 32 KB doubles as GRU A-tiles
  __shared__ __hip_bfloat16 Hs[8][16 * 64];   // 16 KB, per-wave [i_phase][e]
  int tid = threadIdx.x;
  int bx = blockIdx.x;
  int og = bx >> 6, ih = (bx >> 5) & 1, s = bx & 31;
  int lane = tid & 63, lr = lane & 15, lq = lane >> 4;
  int wave = tid >> 6;
  const int ocol = og * 16 + lr;

  // ---- step-invariant msg state (registers, hoisted across all 6 steps) ----
  bf16x8 b2f0, b2f1;
#pragma unroll
  for (int j = 0; j < 8; ++j) {
    int k = lq * 8 + j;
    __bf16 v = *(const __bf16*)(b2t + (size_t)ocol * 64 + ih * 32 + k);
    __bf16 z = (__bf16)0.0f;
    b2f0[j] = (k < 16) ? v : z;
    b2f1[j] = (k >= 16) ? v : z;
  }
  int e0s = s * 1280;
  int nt = (s < 31) ? 20 : 5;  // 40000 = 31*1280 + 320
  int sw0 = (((0 * 4 + lq) ^ lr) * 8);
  int sw1 = (((1 * 4 + lq) ^ lr) * 8);
  int sw2 = (((2 * 4 + lq) ^ lr) * 8);
  int sw3 = (((3 * 4 + lq) ^ lr) * 8);
  // hoisted src for all 3 rounds (step-invariant)
  int se0 = src[e0s + wave * 64 + lane];
  int se1 = (wave + 8 < nt) ? src[e0s + (wave + 8) * 64 + lane] : 0;
  int se2 = (wave + 16 < nt) ? src[e0s + (wave + 16) * 64 + lane] : 0;
  __hip_bfloat16* Hsw = &Hs[wave][0];

  for (int step = 0; step < NSTEPS; ++step) {
    // ---- (re)load W2 slice: full on step 0, only GRU-clobbered rows 0..127 after ----
    int nit = step ? 4 : 16;
    for (int it = 0; it < nit; ++it) {
      int chunk = it * 512 + tid;          // 8192 chunks of 8 elems
      int row = chunk >> 4, c = chunk & 15;
      int ig = row >> 4, ol = row & 15;
      const __hip_bfloat16* gp =
          w2 + ((size_t)((ih * 32 + ig) * 64 + og * 16 + ol)) * EHID + c * 8;
      *(bf16x8*)(W2s + row * 128 + ((c ^ ol) * 8)) = *(const bf16x8*)gp;
    }
    __syncthreads();  // W2s ready

    // =================== msg phase (barrier-free rounds) ===================
#pragma unroll 1
    for (int r3 = 0; r3 < 3; ++r3) {
      int t = r3 * 8 + wave;
      if (t >= nt) break;
      int e0t = e0s + t * 64;
      int s_e = (r3 == 0) ? se0 : (r3 == 1) ? se1 : se2;

      bf16x8 tf[4][4];
#pragma unroll
      for (int mt = 0; mt < 4; ++mt)
#pragma unroll
        for (int ks = 0; ks < 4; ++ks)
          tf[mt][ks] = *(const bf16x8*)(t_bf + (size_t)(e0t + mt * 16 + lr) * EHID +
                                        ks * 32 + lq * 8);
      int4 dv[4];
#pragma unroll
      for (int mt = 0; mt < 4; ++mt)
        dv[mt] = *(const int4*)(dst + e0t + mt * 16 + lq * 4);

      const float* hrow = h + (size_t)s_e * D + ih * 32;
      f32x4 C[4];
#pragma unroll
      for (int mt = 0; mt < 4; ++mt) C[mt] = f32x4{0.f, 0.f, 0.f, 0.f};

#pragma unroll
      for (int ph = 0; ph < 2; ++ph) {
#pragma unroll
        for (int q = 0; q < 4; ++q) {
          float4 hv = *(const float4*)(hrow + ph * 16 + q * 4);
          Hsw[(q * 4 + 0) * 64 + lane] = __float2bfloat16(hv.x);
          Hsw[(q * 4 + 1) * 64 + lane] = __float2bfloat16(hv.y);
          Hsw[(q * 4 + 2) * 64 + lane] = __float2bfloat16(hv.z);
          Hsw[(q * 4 + 3) * 64 + lane] = __float2bfloat16(hv.w);
        }
#pragma unroll
        for (int mt = 0; mt < 4; ++mt) {
          bf16x8 af;
#pragma unroll
          for (int j = 0; j < 8; ++j)
            af[j] = *(const __bf16*)(Hsw + ((lq * 8 + j) & 15) * 64 + mt * 16 + lr);
          C[mt] = __builtin_amdgcn_mfma_f32_16x16x32_bf16(af, ph ? b2f1 : b2f0, C[mt], 0, 0, 0);
        }
        __builtin_amdgcn_s_setprio(1);
#pragma unroll 2
        for (int igl = 0; igl < 16; ++igl) {
          int ig = ph * 16 + igl;
          const __hip_bfloat16* Wr = W2s + (ig * 16 + lr) * 128;
          bf16x8 f0 = *(const bf16x8*)(Wr + sw0);
          bf16x8 f1 = *(const bf16x8*)(Wr + sw1);
          bf16x8 f2 = *(const bf16x8*)(Wr + sw2);
          bf16x8 f3 = *(const bf16x8*)(Wr + sw3);
#pragma unroll
          for (int mt = 0; mt < 4; ++mt) {
            f32x4 P = {0.f, 0.f, 0.f, 0.f};
            P = __builtin_amdgcn_mfma_f32_16x16x32_bf16(tf[mt][0], f0, P, 0, 0, 0);
            P = __builtin_amdgcn_mfma_f32_16x16x32_bf16(tf[mt][1], f1, P, 0, 0, 0);
            P = __builtin_amdgcn_mfma_f32_16x16x32_bf16(tf[mt][2], f2, P, 0, 0, 0);
            P = __builtin_amdgcn_mfma_f32_16x16x32_bf16(tf[mt][3], f3, P, 0, 0, 0);
            uint2 hA = *(const uint2*)(Hsw + igl * 64 + mt * 16 + lq * 4);
            C[mt][0] = fmaf(__uint_as_float(hA.x << 16), P[0], C[mt][0]);
            C[mt][1] = fmaf(__uint_as_float(hA.x & 0xffff0000u), P[1], C[mt][1]);
            C[mt][2] = fmaf(__uint_as_float(hA.y << 16), P[2], C[mt][2]);
            C[mt][3] = fmaf(__uint_as_float(hA.y & 0xffff0000u), P[3], C[mt][3]);
          }
        }
        __builtin_amdgcn_s_setprio(0);
      }
#pragma unroll
      for (int mt = 0; mt < 4; ++mt) {
        atomicAdd(neigh + (size_t)dv[mt].x * D + ocol, C[mt][0]);
        atomicAdd(neigh + (size_t)dv[mt].y * D + ocol, C[mt][1]);
        atomicAdd(neigh + (size_t)dv[mt].z * D + ocol, C[mt][2]);
        atomicAdd(neigh + (size_t)dv[mt].w * D + ocol, C[mt][3]);
      }
    }
    grid.sync();  // all atomics visible device-wide

    // =================== gru phase (overlay in W2s[0..16383]) ===================
    // 2 groups of 32 nodes per rep (waves 0-3 / 4-7), 2 reps -> 1024 slots >= 625
    int g = tid >> 8;              // 0..1
    int lt = tid & 255;
    int wave4 = (tid >> 6) & 3;
    __hip_bfloat16* Ahi = W2s + g * 8192;
    __hip_bfloat16* Alo = Ahi + 4096;
#pragma unroll 1
    for (int rep = 0; rep < 2; ++rep) {
      int gg = rep * 512 + bx * 2 + g;
      if (rep) __syncthreads();    // protect LDS reuse across reps
      if (gg < 625) {
        int n0 = gg * 32;
        for (int idx = lt; idx < 32 * 64; idx += 256) {
          int node = idx >> 6, f = idx & 63;
          int gn = n0 + node;
          float xv = fmaxf(neigh[(size_t)gn * D + f] + cb[f], 0.f);
          neigh[(size_t)gn * D + f] = 0.f;
          float hv = h[(size_t)gn * D + f];
          __hip_bfloat16 xh = __float2bfloat16(xv);
          __hip_bfloat16 hh = __float2bfloat16(hv);
          Ahi[node * 128 + f] = xh;
          Ahi[node * 128 + 64 + f] = hh;
          Alo[node * 128 + f] = __float2bfloat16(xv - __bfloat162float(xh));
          Alo[node * 128 + 64 + f] = __float2bfloat16(hv - __bfloat162float(hh));
        }
      }
      __syncthreads();
      if (gg < 625) {
        int n0 = gg * 32;
        f32x4 acc[2][4] = {};
#pragma unroll
        for (int ks = 0; ks < 4; ++ks) {
          int koff = ks * 32 + lq * 8;
          bf16x8 ah[2], al[2], bh[4], bl[4];
#pragma unroll
          for (int mt = 0; mt < 2; ++mt) {
            ah[mt] = *(const bf16x8*)(Ahi + (mt * 16 + lr) * 128 + koff);
            al[mt] = *(const bf16x8*)(Alo + (mt * 16 + lr) * 128 + koff);
          }
#pragma unroll
          for (int cls = 0; cls < 4; ++cls) {
            int n = cls * 64 + wave4 * 16 + lr;
            bh[cls] = *(const bf16x8*)(Bhi + (size_t)n * 128 + koff);
            bl[cls] = *(const bf16x8*)(Blo + (size_t)n * 128 + koff);
          }
#pragma unroll
          for (int mt = 0; mt < 2; ++mt)
#pragma unroll
            for (int cls = 0; cls < 4; ++cls) {
              acc[mt][cls] = __builtin_amdgcn_mfma_f32_16x16x32_bf16(ah[mt], bh[cls], acc[mt][cls], 0, 0, 0);
              acc[mt][cls] = __builtin_amdgcn_mfma_f32_16x16x32_bf16(al[mt], bh[cls], acc[mt][cls], 0, 0, 0);
              acc[mt][cls] = __builtin_amdgcn_mfma_f32_16x16x32_bf16(ah[mt], bl[cls], acc[mt][cls], 0, 0, 0);
            }
        }
        int o = wave4 * 16 + lr;
        float b_r = bih[o] + bhh[o];
        float b_z = bih[64 + o] + bhh[64 + o];
        float b_in = bih[128 + o];
        float b_hn = bhh[128 + o];
#pragma unroll
        for (int mt = 0; mt < 2; ++mt) {
#pragma unroll
          for (int r = 0; r < 4; ++r) {
            int gn = n0 + mt * 16 + lq * 4 + r;
            float rs = acc[mt][0][r] + b_r;
            float zs = acc[mt][1][r] + b_z;
            float inn = acc[mt][2][r] + b_in;
            float hnn = acc[mt][3][r] + b_hn;
            float rg = 1.f / (1.f + __expf(-rs));
            float zg = 1.f / (1.f + __expf(-zs));
            float a = inn + rg * hnn;
            a = fminf(fmaxf(a, -15.f), 15.f);
            float e2 = __expf(2.f * a);
            float nn = (e2 - 1.f) / (e2 + 1.f);
            float hold = h[(size_t)gn * D + o];
            h[(size_t)gn * D + o] = (1.f - zg) * nn + zg * hold;
          }
        }
      }
    }
    grid.sync();  // h updated device-wide; W2s free to reload
  }

  // =================== pred phase ===================
  int gw = bx * 8 + wave;
  for (int e = gw; e < NE; e += 2048) {
    int sE = src[e], dE = dst[e];
    float v = h[(size_t)sE * D + lane] * pW[lane] + h[(size_t)dE * D + lane] * pW[64 + lane];
#pragma unroll
    for (int off = 32; off >= 1; off >>= 1) v += __shfl_xor(v, off, 64);
    if (lane == 0) out[e] = v + pb[0];
  }
}

extern "C" void kernel_launch(void* const* d_in, const int* in_sizes, int n_in,
                              void* d_out, int out_size, void* d_ws, size_t ws_size,
                              hipStream_t stream) {
  const float* node_feats = (const float*)d_in[0];
  const float* edge_feats = (const float*)d_in[1];
  const int* src = (const int*)d_in[2];
  const int* dst = (const int*)d_in[3];
  const float* proj_W = (const float*)d_in[4];
  const float* proj_b = (const float*)d_in[5];
  const float* en_W1 = (const float*)d_in[6];
  const float* en_b1 = (const float*)d_in[7];
  const float* en_W2 = (const float*)d_in[8];
  const float* en_b2 = (const float*)d_in[9];
  const float* conv_b = (const float*)d_in[10];
  const float* gru_Wih = (const float*)d_in[11];
  const float* gru_Whh = (const float*)d_in[12];
  const float* gru_bih = (const float*)d_in[13];
  const float* gru_bhh = (const float*)d_in[14];
  const float* pred_W = (const float*)d_in[15];
  const float* pred_b = (const float*)d_in[16];

  char* ws = (char*)d_ws;
  size_t off = 0;
  auto walloc = [&](size_t bytes) -> void* {
    void* p = ws + off;
    off = (off + bytes + 255) & ~(size_t)255;
    return p;
  };
  float* h = (float*)walloc((size_t)NV * D * 4);
  float* neigh = (float*)walloc((size_t)NV * D * 4);
  __hip_bfloat16* t_bf = (__hip_bfloat16*)walloc((size_t)NE * EHID * 2);
  __hip_bfloat16* w2_bf = (__hip_bfloat16*)walloc((size_t)D * D * EHID * 2);
  __hip_bfloat16* b2t = (__hip_bfloat16*)walloc((size_t)D * D * 2);
  __hip_bfloat16* Bhi = (__hip_bfloat16*)walloc((size_t)256 * 128 * 2);
  __hip_bfloat16* Blo = (__hip_bfloat16*)walloc((size_t)256 * 128 * 2);
  float* outp = (float*)d_out;

  k_prep<<<27192, 256, 0, stream>>>(node_feats, proj_W, proj_b, h, neigh,
                                    edge_feats, en_W1, en_b1, t_bf,
                                    en_W2, w2_bf, en_b2, b2t,
                                    gru_Wih, gru_Whh, Bhi, Blo);
  void* args[] = {(void*)&h, (void*)&t_bf, (void*)&w2_bf, (void*)&b2t,
                  (void*)&src, (void*)&dst, (void*)&neigh,
                  (void*)&Bhi, (void*)&Blo, (void*)&conv_b,
                  (void*)&gru_bih, (void*)&gru_bhh,
                  (void*)&pred_W, (void*)&pred_b, (void*)&outp};
  hipLaunchCooperativeKernel((void*)k_steps, dim3(256), dim3(512), args, 0, stream);
}

// Round 6
// 488.170 us; speedup vs baseline: 1.9094x; 1.9094x over previous
//
#include <hip/hip_runtime.h>
#include <hip/hip_bf16.h>
#include <cstdint>

#define NV 20000
#define NE 40000
#define NODE_IN 74
#define EDGE_IN 12
#define D 64
#define EHID 128
#define NSTEPS 6

typedef __bf16 bf16x8 __attribute__((ext_vector_type(8)));
typedef float f32x4 __attribute__((ext_vector_type(4)));

// ------- fused prep: proj | edge1 | cvt_w2 | b2t | build_b (validated R4) -------
__global__ __launch_bounds__(256) void k_prep(
    const float* __restrict__ nf, const float* __restrict__ pjW, const float* __restrict__ pjb,
    float* __restrict__ h, float* __restrict__ neigh,
    const float* __restrict__ ef, const float* __restrict__ W1, const float* __restrict__ b1,
    __hip_bfloat16* __restrict__ t_bf,
    const float* __restrict__ W2, __hip_bfloat16* __restrict__ w2b,
    const float* __restrict__ b2, __hip_bfloat16* __restrict__ b2t,
    const float* __restrict__ Wih, const float* __restrict__ Whh,
    __hip_bfloat16* __restrict__ Bhi, __hip_bfloat16* __restrict__ Blo) {
  __shared__ float smem[4 * NODE_IN];
  int tid = threadIdx.x;
  int bx = blockIdx.x;
  if (bx < 5000) {                    // ---- node projection: 4 nodes/block ----
    int nb = bx * 4;
    for (int idx = tid; idx < 4 * NODE_IN; idx += 256)
      smem[idx] = nf[(size_t)nb * NODE_IN + idx];
    __syncthreads();
    int nl = tid >> 6, o = tid & 63;
    float acc = pjb[o];
#pragma unroll
    for (int i = 0; i < NODE_IN; ++i) acc = fmaf(smem[nl * NODE_IN + i], pjW[o * NODE_IN + i], acc);
    h[(size_t)(nb + nl) * D + o] = fmaxf(acc, 0.f);
    neigh[(size_t)(nb + nl) * D + o] = 0.f;
  } else if (bx < 25000) {            // ---- edge net layer 1: 2 edges/block ----
    int eb = (bx - 5000) * 2;
    if (tid < 2 * EDGE_IN)
      smem[tid] = ef[(size_t)eb * EDGE_IN + tid];
    __syncthreads();
    int el = tid >> 7, k = tid & 127;
    float acc = b1[k];
#pragma unroll
    for (int j = 0; j < EDGE_IN; ++j) acc = fmaf(smem[el * EDGE_IN + j], W1[k * EDGE_IN + j], acc);
    t_bf[(size_t)(eb + el) * EHID + k] = __float2bfloat16(fmaxf(acc, 0.f));
  } else if (bx < 27048) {            // ---- W2 fp32 -> bf16 ----
    int idx = (bx - 25000) * 256 + tid;
    w2b[idx] = __float2bfloat16(W2[idx]);
  } else if (bx < 27064) {            // ---- b2 transpose ----
    int idx = (bx - 27048) * 256 + tid;
    int o = idx >> 6, i = idx & 63;
    b2t[o * 64 + i] = __float2bfloat16(b2[i * 64 + o]);
  } else {                            // ---- GRU B matrix, hi/lo split ----
    int idx = (bx - 27064) * 256 + tid;
    int n = idx >> 7, k = idx & 127;
    int o = n & 63, cls = n >> 6;
    float v;
    if (cls == 0)      v = (k < 64) ? Wih[o * 64 + k]         : Whh[o * 64 + (k - 64)];
    else if (cls == 1) v = (k < 64) ? Wih[(64 + o) * 64 + k]  : Whh[(64 + o) * 64 + (k - 64)];
    else if (cls == 2) v = (k < 64) ? Wih[(128 + o) * 64 + k] : 0.f;
    else               v = (k < 64) ? 0.f                     : Whh[(128 + o) * 64 + (k - 64)];
    __hip_bfloat16 hi = __float2bfloat16(v);
    Bhi[idx] = hi;
    Blo[idx] = __float2bfloat16(v - __bfloat162float(hi));
  }
}

// ------- fused NNConv message+aggregate: R0-EXACT body (proven 47.1us) + setprio -------
// R1/R2/R4/R5 bracketed the space: more TLP doesn't help, coop fusion hurts
// (grid.sync ~40us). This body at 47us = ~893 TF effective = the plain-HIP
// structural ceiling for this kernel class. Only numerically-free addition:
// s_setprio(1) around the MFMA inner loop (T5 regime: barrier-free, role-diverse).
__global__ __launch_bounds__(512, 2) void k_msg(const float* __restrict__ h,
                                                const __hip_bfloat16* __restrict__ t_bf,
                                                const __hip_bfloat16* __restrict__ w2,
                                                const __hip_bfloat16* __restrict__ b2t,
                                                const int* __restrict__ src,
                                                const int* __restrict__ dst,
                                                float* __restrict__ neigh) {
  __shared__ __hip_bfloat16 W2s[512 * 128];   // 128 KB, row = ig*16+ol, swizzled k-chunks
  __shared__ __hip_bfloat16 Hs[8][16 * 64];   // 16 KB, per-wave [i_phase][e] bf16
  int tid = threadIdx.x;
  int bx = blockIdx.x;
  int cg = bx >> 6, ih = (bx >> 5) & 1, s = bx & 31;
  int lane = tid & 63, lr = lane & 15, lq = lane >> 4;
  int wave = tid >> 6;
  const int ocol = cg * 16 + lr;

  // ---- load W2 slice into LDS (once) ----
#pragma unroll
  for (int it = 0; it < 16; ++it) {
    int chunk = it * 512 + tid;          // 8192 chunks of 8 elems
    int row = chunk >> 4, c = chunk & 15;
    int ig = row >> 4, ol = row & 15;
    const __hip_bfloat16* gp =
        w2 + ((size_t)((ih * 32 + ig) * 64 + cg * 16 + ol)) * EHID + c * 8;
    *(bf16x8*)(W2s + row * 128 + ((c ^ ol) * 8)) = *(const bf16x8*)gp;
  }
  // phase-masked b2 B-frags (k = lq*8+j over this block's 32-i slice)
  bf16x8 b2f0, b2f1;
#pragma unroll
  for (int j = 0; j < 8; ++j) {
    int k = lq * 8 + j;
    __bf16 v = *(const __bf16*)(b2t + (size_t)ocol * 64 + ih * 32 + k);
    __bf16 z = (__bf16)0.0f;
    b2f0[j] = (k < 16) ? v : z;
    b2f1[j] = (k >= 16) ? v : z;
  }
  __syncthreads();  // W2s ready — the ONLY barrier

  __hip_bfloat16* Hsw = &Hs[wave][0];
  int e0s = s * 1280;
  int nt = (s < 31) ? 20 : 5;  // 40000 = 31*1280 + 320

  // swizzled per-lane k-chunk offsets
  int sw0 = (((0 * 4 + lq) ^ lr) * 8);
  int sw1 = (((1 * 4 + lq) ^ lr) * 8);
  int sw2 = (((2 * 4 + lq) ^ lr) * 8);
  int sw3 = (((3 * 4 + lq) ^ lr) * 8);

#pragma unroll 1
  for (int r3 = 0; r3 < 3; ++r3) {
    int t = r3 * 8 + wave;
    if (t >= nt) break;     // divergence is fine: no barriers below
    int e0t = e0s + t * 64;

    // t-frags for this tile's 4 m-tiles
    bf16x8 tf[4][4];
#pragma unroll
    for (int mt = 0; mt < 4; ++mt)
#pragma unroll
      for (int ks = 0; ks < 4; ++ks)
        tf[mt][ks] = *(const bf16x8*)(t_bf + (size_t)(e0t + mt * 16 + lr) * EHID +
                                      ks * 32 + lq * 8);

    int s_e = src[e0t + lane];
    const float* hrow = h + (size_t)s_e * D + ih * 32;
    f32x4 C[4];
#pragma unroll
    for (int mt = 0; mt < 4; ++mt) C[mt] = f32x4{0.f, 0.f, 0.f, 0.f};

#pragma unroll
    for (int ph = 0; ph < 2; ++ph) {
      // gather this phase's 16 i's for all 64 edges (wave-private; no barrier)
#pragma unroll
      for (int q = 0; q < 4; ++q) {
        float4 hv = *(const float4*)(hrow + ph * 16 + q * 4);
        Hsw[(q * 4 + 0) * 64 + lane] = __float2bfloat16(hv.x);
        Hsw[(q * 4 + 1) * 64 + lane] = __float2bfloat16(hv.y);
        Hsw[(q * 4 + 2) * 64 + lane] = __float2bfloat16(hv.z);
        Hsw[(q * 4 + 3) * 64 + lane] = __float2bfloat16(hv.w);
      }
      // b2-term partial for this phase (masked frag zeroes out-of-phase k)
#pragma unroll
      for (int mt = 0; mt < 4; ++mt) {
        bf16x8 af;
#pragma unroll
        for (int j = 0; j < 8; ++j)
          af[j] = *(const __bf16*)(Hsw + ((lq * 8 + j) & 15) * 64 + mt * 16 + lr);
        C[mt] = __builtin_amdgcn_mfma_f32_16x16x32_bf16(af, ph ? b2f1 : b2f0, C[mt], 0, 0, 0);
      }
      // inner: 16 i's of this phase
      __builtin_amdgcn_s_setprio(1);
#pragma unroll 2
      for (int igl = 0; igl < 16; ++igl) {
        int ig = ph * 16 + igl;
        const __hip_bfloat16* Wr = W2s + (ig * 16 + lr) * 128;
        bf16x8 f0 = *(const bf16x8*)(Wr + sw0);
        bf16x8 f1 = *(const bf16x8*)(Wr + sw1);
        bf16x8 f2 = *(const bf16x8*)(Wr + sw2);
        bf16x8 f3 = *(const bf16x8*)(Wr + sw3);
#pragma unroll
        for (int mt = 0; mt < 4; ++mt) {
          f32x4 P = {0.f, 0.f, 0.f, 0.f};
          P = __builtin_amdgcn_mfma_f32_16x16x32_bf16(tf[mt][0], f0, P, 0, 0, 0);
          P = __builtin_amdgcn_mfma_f32_16x16x32_bf16(tf[mt][1], f1, P, 0, 0, 0);
          P = __builtin_amdgcn_mfma_f32_16x16x32_bf16(tf[mt][2], f2, P, 0, 0, 0);
          P = __builtin_amdgcn_mfma_f32_16x16x32_bf16(tf[mt][3], f3, P, 0, 0, 0);
          uint2 hA = *(const uint2*)(Hsw + igl * 64 + mt * 16 + lq * 4);
          C[mt][0] = fmaf(__uint_as_float(hA.x << 16), P[0], C[mt][0]);
          C[mt][1] = fmaf(__uint_as_float(hA.x & 0xffff0000u), P[1], C[mt][1]);
          C[mt][2] = fmaf(__uint_as_float(hA.y << 16), P[2], C[mt][2]);
          C[mt][3] = fmaf(__uint_as_float(hA.y & 0xffff0000u), P[3], C[mt][3]);
        }
      }
      __builtin_amdgcn_s_setprio(0);
    }
    // scatter-add (i-halves merge via atomics); overlaps next tile (no barrier)
#pragma unroll
    for (int mt = 0; mt < 4; ++mt) {
#pragma unroll
      for (int r = 0; r < 4; ++r) {
        int ea = e0t + mt * 16 + lq * 4 + r;
        atomicAdd(neigh + (size_t)dst[ea] * D + ocol, C[mt][r]);
      }
    }
  }
}

// ------- GRU: 32 nodes/block; re-zeroes neigh; LAST step also emits per-node
// predictor partials a[v]=h[v]�pW[:64], b[v]=h[v]�pW[64:] (block owns its nodes,
// h is L1-hot) so k_pred collapses to a 2-load gather. -------
__global__ __launch_bounds__(256) void k_gru(float* __restrict__ neigh,
                                             float* __restrict__ h,
                                             const __hip_bfloat16* __restrict__ Bhi,
                                             const __hip_bfloat16* __restrict__ Blo,
                                             const float* __restrict__ cb,
                                             const float* __restrict__ bih,
                                             const float* __restrict__ bhh,
                                             const float* __restrict__ pW,
                                             float* __restrict__ pa,
                                             float* __restrict__ pbv,
                                             int last) {
  __shared__ __hip_bfloat16 Ahi[32 * 128];
  __shared__ __hip_bfloat16 Alo[32 * 128];
  int tid = threadIdx.x;
  int n0 = blockIdx.x * 32;  // NV % 32 == 0
  for (int idx = tid; idx < 32 * 64; idx += 256) {
    int node = idx >> 6, f = idx & 63;
    int gn = n0 + node;
    float xv = fmaxf(neigh[(size_t)gn * D + f] + cb[f], 0.f);
    neigh[(size_t)gn * D + f] = 0.f;
    float hv = h[(size_t)gn * D + f];
    __hip_bfloat16 xh = __float2bfloat16(xv);
    __hip_bfloat16 hh = __float2bfloat16(hv);
    Ahi[node * 128 + f] = xh;
    Ahi[node * 128 + 64 + f] = hh;
    Alo[node * 128 + f] = __float2bfloat16(xv - __bfloat162float(xh));
    Alo[node * 128 + 64 + f] = __float2bfloat16(hv - __bfloat162float(hh));
  }
  __syncthreads();
  int wave = tid >> 6, lane = tid & 63;
  int lr = lane & 15, lq = lane >> 4;
  f32x4 acc[2][4] = {};
#pragma unroll
  for (int ks = 0; ks < 4; ++ks) {
    int koff = ks * 32 + lq * 8;
    bf16x8 ah[2], al[2], bh[4], bl[4];
#pragma unroll
    for (int mt = 0; mt < 2; ++mt) {
      ah[mt] = *(const bf16x8*)(Ahi + (mt * 16 + lr) * 128 + koff);
      al[mt] = *(const bf16x8*)(Alo + (mt * 16 + lr) * 128 + koff);
    }
#pragma unroll
    for (int cls = 0; cls < 4; ++cls) {
      int n = cls * 64 + wave * 16 + lr;
      bh[cls] = *(const bf16x8*)(Bhi + (size_t)n * 128 + koff);
      bl[cls] = *(const bf16x8*)(Blo + (size_t)n * 128 + koff);
    }
#pragma unroll
    for (int mt = 0; mt < 2; ++mt)
#pragma unroll
      for (int cls = 0; cls < 4; ++cls) {
        acc[mt][cls] = __builtin_amdgcn_mfma_f32_16x16x32_bf16(ah[mt], bh[cls], acc[mt][cls], 0, 0, 0);
        acc[mt][cls] = __builtin_amdgcn_mfma_f32_16x16x32_bf16(al[mt], bh[cls], acc[mt][cls], 0, 0, 0);
        acc[mt][cls] = __builtin_amdgcn_mfma_f32_16x16x32_bf16(ah[mt], bl[cls], acc[mt][cls], 0, 0, 0);
      }
  }
  int o = wave * 16 + lr;
  float b_r = bih[o] + bhh[o];
  float b_z = bih[64 + o] + bhh[64 + o];
  float b_in = bih[128 + o];
  float b_hn = bhh[128 + o];
#pragma unroll
  for (int mt = 0; mt < 2; ++mt) {
#pragma unroll
    for (int r = 0; r < 4; ++r) {
      int gn = n0 + mt * 16 + lq * 4 + r;
      float rs = acc[mt][0][r] + b_r;
      float zs = acc[mt][1][r] + b_z;
      float inn = acc[mt][2][r] + b_in;
      float hnn = acc[mt][3][r] + b_hn;
      float rg = 1.f / (1.f + __expf(-rs));
      float zg = 1.f / (1.f + __expf(-zs));
      float a = inn + rg * hnn;
      a = fminf(fmaxf(a, -15.f), 15.f);
      float e2 = __expf(2.f * a);
      float nn = (e2 - 1.f) / (e2 + 1.f);
      float hold = h[(size_t)gn * D + o];
      h[(size_t)gn * D + o] = (1.f - zg) * nn + zg * hold;
    }
  }
  if (last) {
    __syncthreads();  // all of this block's h writes retired (same-CU L1 coherent)
    int node = tid >> 3, o0 = (tid & 7) * 8;   // 32 nodes x 8 lanes x 8 o's
    int gn = n0 + node;
    float sa = 0.f, sb = 0.f;
#pragma unroll
    for (int j = 0; j < 8; ++j) {
      float hv = h[(size_t)gn * D + o0 + j];
      sa = fmaf(hv, pW[o0 + j], sa);
      sb = fmaf(hv, pW[64 + o0 + j], sb);
    }
#pragma unroll
    for (int off = 4; off >= 1; off >>= 1) {
      sa += __shfl_xor(sa, off, 64);
      sb += __shfl_xor(sb, off, 64);
    }
    if ((tid & 7) == 0) { pa[gn] = sa; pbv[gn] = sb; }
  }
}

// ---------------- predictor: out[e] = a[src] + b[dst] + pb ----------------
__global__ __launch_bounds__(256) void k_pred(const float* __restrict__ pa,
                                              const float* __restrict__ pbv,
                                              const int* __restrict__ src,
                                              const int* __restrict__ dst,
                                              const float* __restrict__ pb,
                                              float* __restrict__ out) {
  int e = blockIdx.x * 256 + threadIdx.x;
  if (e < NE) out[e] = pa[src[e]] + pbv[dst[e]] + pb[0];
}

extern "C" void kernel_launch(void* const* d_in, const int* in_sizes, int n_in,
                              void* d_out, int out_size, void* d_ws, size_t ws_size,
                              hipStream_t stream) {
  const float* node_feats = (const float*)d_in[0];
  const float* edge_feats = (const float*)d_in[1];
  const int* src = (const int*)d_in[2];
  const int* dst = (const int*)d_in[3];
  const float* proj_W = (const float*)d_in[4];
  const float* proj_b = (const float*)d_in[5];
  const float* en_W1 = (const float*)d_in[6];
  const float* en_b1 = (const float*)d_in[7];
  const float* en_W2 = (const float*)d_in[8];
  const float* en_b2 = (const float*)d_in[9];
  const float* conv_b = (const float*)d_in[10];
  const float* gru_Wih = (const float*)d_in[11];
  const float* gru_Whh = (const float*)d_in[12];
  const float* gru_bih = (const float*)d_in[13];
  const float* gru_bhh = (const float*)d_in[14];
  const float* pred_W = (const float*)d_in[15];
  const float* pred_b = (const float*)d_in[16];

  char* ws = (char*)d_ws;
  size_t off = 0;
  auto walloc = [&](size_t bytes) -> void* {
    void* p = ws + off;
    off = (off + bytes + 255) & ~(size_t)255;
    return p;
  };
  float* h = (float*)walloc((size_t)NV * D * 4);
  float* neigh = (float*)walloc((size_t)NV * D * 4);
  __hip_bfloat16* t_bf = (__hip_bfloat16*)walloc((size_t)NE * EHID * 2);
  __hip_bfloat16* w2_bf = (__hip_bfloat16*)walloc((size_t)D * D * EHID * 2);
  __hip_bfloat16* b2t = (__hip_bfloat16*)walloc((size_t)D * D * 2);
  __hip_bfloat16* Bhi = (__hip_bfloat16*)walloc((size_t)256 * 128 * 2);
  __hip_bfloat16* Blo = (__hip_bfloat16*)walloc((size_t)256 * 128 * 2);
  float* pa = (float*)walloc((size_t)NV * 4);
  float* pbv = (float*)walloc((size_t)NV * 4);

  k_prep<<<27192, 256, 0, stream>>>(node_feats, proj_W, proj_b, h, neigh,
                                    edge_feats, en_W1, en_b1, t_bf,
                                    en_W2, w2_bf, en_b2, b2t,
                                    gru_Wih, gru_Whh, Bhi, Blo);
  for (int s = 0; s < NSTEPS; ++s) {
    k_msg<<<256, 512, 0, stream>>>(h, t_bf, w2_bf, b2t, src, dst, neigh);
    k_gru<<<NV / 32, 256, 0, stream>>>(neigh, h, Bhi, Blo, conv_b, gru_bih, gru_bhh,
                                       pred_W, pa, pbv, (s == NSTEPS - 1) ? 1 : 0);
  }
  k_pred<<<(NE + 255) / 256, 256, 0, stream>>>(pa, pbv, src, dst, pred_b, (float*)d_out);
}